// Round 4
// baseline (8713.288 us; speedup 1.0000x reference)
//
#include <hip/hip_runtime.h>
#include <math.h>

#define S_LEN 2048
#define H_DIM 1024
#define NHQ 16
#define D_HEAD 64
#define FF_DIM 4096
#define NLAYER 2
#define EPSV 1e-6f

typedef unsigned short ushortt;
typedef __attribute__((ext_vector_type(8))) short bf16x8;
typedef __attribute__((ext_vector_type(4))) short bf16x4;
typedef __attribute__((ext_vector_type(4))) float f32x4;

__device__ __forceinline__ float bf2f(ushortt u) {
    union { float f; unsigned u; } c; c.u = ((unsigned)u) << 16; return c.f;
}
__device__ __forceinline__ ushortt f2bf(float f) {
    union { float f; unsigned u; } c; c.f = f;
    unsigned r = c.u + 0x7fff + ((c.u >> 16) & 1);
    return (ushortt)(r >> 16);
}

// ---------------- f32 -> bf16 convert (weights), 8 elems/thread ----------------
__global__ __launch_bounds__(256) void f2b_k(const float* __restrict__ in,
                                             ushortt* __restrict__ out, long n) {
    long i8 = ((long)blockIdx.x * 256 + threadIdx.x) * 8;
    if (i8 >= n) return;
    f32x4 a = *(const f32x4*)&in[i8];
    f32x4 b = *(const f32x4*)&in[i8 + 4];
    bf16x8 o;
    #pragma unroll
    for (int j = 0; j < 4; j++) { o[j] = (short)f2bf(a[j]); o[4 + j] = (short)f2bf(b[j]); }
    *(bf16x8*)&out[i8] = o;
}

// ---------------- embedding gather: x_f32[row] = embed[ids[row]] ----------------
__global__ __launch_bounds__(256) void gather_k(const int* __restrict__ ids,
                                                const float* __restrict__ emb,
                                                float* __restrict__ x) {
    int row = blockIdx.x, tid = threadIdx.x;
    long id = ids[row];
    f32x4 e = *((const f32x4*)emb + id * (H_DIM / 4) + tid);
    *(f32x4*)&x[(long)row * H_DIM + tid * 4] = e;
}

// ---------------- rmsnorm: h_bf16 = x * rsqrt(mean(x^2)+eps) * w ----------------
__global__ __launch_bounds__(256) void rmsnorm_k(const float* __restrict__ x,
                                                 const float* __restrict__ w,
                                                 ushortt* __restrict__ out) {
    __shared__ float red[4];
    int row = blockIdx.x, tid = threadIdx.x;
    f32x4 v = *(const f32x4*)&x[(long)row * H_DIM + tid * 4];
    float ss = v[0]*v[0] + v[1]*v[1] + v[2]*v[2] + v[3]*v[3];
    #pragma unroll
    for (int off = 1; off < 64; off <<= 1) ss += __shfl_xor(ss, off, 64);
    if ((tid & 63) == 0) red[tid >> 6] = ss;
    __syncthreads();
    float tot = red[0] + red[1] + red[2] + red[3];
    float rs = rsqrtf(tot / (float)H_DIM + EPSV);
    f32x4 wv = *(const f32x4*)&w[tid * 4];
    #pragma unroll
    for (int j = 0; j < 4; j++)
        out[(long)row * H_DIM + tid * 4 + j] = f2bf(v[j] * rs * wv[j]);
}

// ---------------- GEMM: C[M,N] = A[M,K] * B[N,K]^T, bf16 in, MFMA ----------------
// EPI 0: out bf16 [M,N];  EPI 1: out f32 [M,N] +=
template <int EPI>
__global__ __launch_bounds__(256) void gemm_bt(const ushortt* __restrict__ A,
                                               const ushortt* __restrict__ B,
                                               void* __restrict__ out,
                                               int M, int N, int K) {
    __shared__ ushortt As[64 * 40];
    __shared__ ushortt Bs[64 * 40];
    const int tid = threadIdx.x;
    const int lane = tid & 63;
    const int w = tid >> 6;
    const int wm = w >> 1, wn = w & 1;
    const int m0 = blockIdx.y * 64, n0 = blockIdx.x * 64;
    const int srow = tid >> 2, sc8 = (tid & 3) * 8;
    const int r15 = lane & 15, g = lane >> 4;

    f32x4 acc[2][2] = {};

    for (int k0 = 0; k0 < K; k0 += 32) {
        *(bf16x8*)&As[srow * 40 + sc8] = *(const bf16x8*)&A[(long)(m0 + srow) * K + k0 + sc8];
        *(bf16x8*)&Bs[srow * 40 + sc8] = *(const bf16x8*)&B[(long)(n0 + srow) * K + k0 + sc8];
        __syncthreads();
        bf16x8 a[2], b[2];
        #pragma unroll
        for (int m = 0; m < 2; m++) a[m] = *(bf16x8*)&As[(wm * 32 + m * 16 + r15) * 40 + g * 8];
        #pragma unroll
        for (int n = 0; n < 2; n++) b[n] = *(bf16x8*)&Bs[(wn * 32 + n * 16 + r15) * 40 + g * 8];
        #pragma unroll
        for (int m = 0; m < 2; m++)
            #pragma unroll
            for (int n = 0; n < 2; n++)
                acc[m][n] = __builtin_amdgcn_mfma_f32_16x16x32_bf16(a[m], b[n], acc[m][n], 0, 0, 0);
        __syncthreads();
    }

    #pragma unroll
    for (int m = 0; m < 2; m++)
        #pragma unroll
        for (int n = 0; n < 2; n++)
            #pragma unroll
            for (int r = 0; r < 4; r++) {
                int row = m0 + wm * 32 + m * 16 + g * 4 + r;
                int col = n0 + wn * 32 + n * 16 + r15;
                float v = acc[m][n][r];
                if (EPI == 0) ((ushortt*)out)[(long)row * N + col] = f2bf(v);
                else ((float*)out)[(long)row * N + col] += v;
            }
}

// ---------------- RoPE (rotate-half), in place on bf16 [S, nheads*64] ----------------
__global__ __launch_bounds__(256) void rope_k(ushortt* __restrict__ p, int nheads) {
    int idx = blockIdx.x * 256 + threadIdx.x;
    int total = S_LEN * nheads * 32;
    if (idx >= total) return;
    int i = idx & 31;
    int hd = (idx >> 5) % nheads;
    int s = idx / (32 * nheads);
    long base = (long)s * (nheads * 64) + hd * 64 + i;
    float x1 = bf2f(p[base]), x2 = bf2f(p[base + 32]);
    float inv = expf(-((2.f * i) / 64.f) * 9.210340371976184f); // ln(10000)
    float f = (float)s * inv;
    float sn, cs;
    sincosf(f, &sn, &cs);
    p[base] = f2bf(x1 * cs - x2 * sn);
    p[base + 32] = f2bf(x2 * cs + x1 * sn);
}

// ---------------- naive attention: one wave per (query, head), lane = d ----------------
// q:[S,H] roped, k:[S,64] roped, v:[S,64]; non-causal, MQA
__global__ __launch_bounds__(64) void attn_naive_k(const ushortt* __restrict__ q,
                                                   const ushortt* __restrict__ k,
                                                   const ushortt* __restrict__ v,
                                                   ushortt* __restrict__ o) {
    const int lane = threadIdx.x;      // = d index
    const int h = blockIdx.y;
    const int qi = blockIdx.x;         // query index
    float qv = bf2f(q[(long)qi * H_DIM + h * D_HEAD + lane]);
    float m = -INFINITY, l = 0.f, acc = 0.f;
    for (int j = 0; j < S_LEN; j++) {
        float kd = bf2f(k[(long)j * D_HEAD + lane]);
        float s = qv * kd;
        #pragma unroll
        for (int off = 1; off < 64; off <<= 1) s += __shfl_xor(s, off, 64);
        s *= 0.125f;  // 1/sqrt(64)
        float mnew = fmaxf(m, s);
        float alpha = __expf(m - mnew);
        float p = __expf(s - mnew);
        l = l * alpha + p;
        acc = acc * alpha + p * bf2f(v[(long)j * D_HEAD + lane]);
        m = mnew;
    }
    o[(long)qi * H_DIM + h * D_HEAD + lane] = f2bf(acc / l);
}

// ---------------- silu(g)*u ----------------
__global__ __launch_bounds__(256) void silu_mul_k(const ushortt* __restrict__ g,
                                                  const ushortt* __restrict__ u,
                                                  ushortt* __restrict__ out, int n) {
    int idx = blockIdx.x * 256 + threadIdx.x;
    if (idx >= n) return;
    float a = bf2f(g[idx]);
    float b = bf2f(u[idx]);
    float r = (a / (1.f + __expf(-a))) * b;
    out[idx] = f2bf(r);
}

// ---------------- final copy f32 -> f32 out ----------------
__global__ __launch_bounds__(256) void copy_out_k(const float* __restrict__ x,
                                                  float* __restrict__ out, int n4) {
    int idx = blockIdx.x * 256 + threadIdx.x;
    if (idx >= n4) return;
    *(f32x4*)&out[(long)idx * 4] = *(const f32x4*)&x[(long)idx * 4];
}

extern "C" void kernel_launch(void* const* d_in, const int* in_sizes, int n_in,
                              void* d_out, int out_size, void* d_ws, size_t ws_size,
                              hipStream_t stream) {
    const int* ids = (const int*)d_in[0];
    const float* emb = (const float*)d_in[1];
    const float* Wq = (const float*)d_in[2];
    const float* Wk = (const float*)d_in[3];
    const float* Wv = (const float*)d_in[4];
    const float* Wo = (const float*)d_in[5];
    const float* Wg = (const float*)d_in[6];
    const float* Wu = (const float*)d_in[7];
    const float* Wd = (const float*)d_in[8];
    const float* ln1 = (const float*)d_in[9];
    const float* ln2 = (const float*)d_in[10];

    char* ws = (char*)d_ws;
    float* x = (float*)ws;        ws += (size_t)S_LEN * H_DIM * 4;
    ushortt* h = (ushortt*)ws;    ws += (size_t)S_LEN * H_DIM * 2;
    ushortt* qb = (ushortt*)ws;   ws += (size_t)S_LEN * H_DIM * 2;
    ushortt* kb = (ushortt*)ws;   ws += (size_t)S_LEN * D_HEAD * 2;
    ushortt* vb = (ushortt*)ws;   ws += (size_t)S_LEN * D_HEAD * 2;
    ushortt* ob = (ushortt*)ws;   ws += (size_t)S_LEN * H_DIM * 2;
    ushortt* gb = (ushortt*)ws;   ws += (size_t)S_LEN * FF_DIM * 2;
    ushortt* ub = (ushortt*)ws;   ws += (size_t)S_LEN * FF_DIM * 2;
    ushortt* wt = (ushortt*)ws;   ws += (size_t)FF_DIM * H_DIM * 2;  // weight convert scratch

    auto conv = [&](const float* src, long n) {
        f2b_k<<<(int)((n / 8 + 255) / 256), 256, 0, stream>>>(src, wt, n);
    };

    gather_k<<<S_LEN, 256, 0, stream>>>(ids, emb, x);

    for (int l = 0; l < NLAYER; l++) {
        rmsnorm_k<<<S_LEN, 256, 0, stream>>>(x, ln1 + (long)l * H_DIM, h);

        conv(Wq + (long)l * H_DIM * H_DIM, (long)H_DIM * H_DIM);
        gemm_bt<0><<<dim3(H_DIM / 64, S_LEN / 64), 256, 0, stream>>>(h, wt, qb, S_LEN, H_DIM, H_DIM);
        conv(Wk + (long)l * D_HEAD * H_DIM, (long)D_HEAD * H_DIM);
        gemm_bt<0><<<dim3(1, S_LEN / 64), 256, 0, stream>>>(h, wt, kb, S_LEN, D_HEAD, H_DIM);
        conv(Wv + (long)l * D_HEAD * H_DIM, (long)D_HEAD * H_DIM);
        gemm_bt<0><<<dim3(1, S_LEN / 64), 256, 0, stream>>>(h, wt, vb, S_LEN, D_HEAD, H_DIM);

        rope_k<<<(S_LEN * NHQ * 32 + 255) / 256, 256, 0, stream>>>(qb, NHQ);
        rope_k<<<(S_LEN * 1 * 32 + 255) / 256, 256, 0, stream>>>(kb, 1);
        attn_naive_k<<<dim3(S_LEN, NHQ), 64, 0, stream>>>(qb, kb, vb, ob);

        conv(Wo + (long)l * H_DIM * H_DIM, (long)H_DIM * H_DIM);
        gemm_bt<1><<<dim3(H_DIM / 64, S_LEN / 64), 256, 0, stream>>>(ob, wt, x, S_LEN, H_DIM, H_DIM);

        rmsnorm_k<<<S_LEN, 256, 0, stream>>>(x, ln2 + (long)l * H_DIM, h);

        conv(Wg + (long)l * FF_DIM * H_DIM, (long)FF_DIM * H_DIM);
        gemm_bt<0><<<dim3(FF_DIM / 64, S_LEN / 64), 256, 0, stream>>>(h, wt, gb, S_LEN, FF_DIM, H_DIM);
        conv(Wu + (long)l * FF_DIM * H_DIM, (long)FF_DIM * H_DIM);
        gemm_bt<0><<<dim3(FF_DIM / 64, S_LEN / 64), 256, 0, stream>>>(h, wt, ub, S_LEN, FF_DIM, H_DIM);
        silu_mul_k<<<(S_LEN * FF_DIM + 255) / 256, 256, 0, stream>>>(gb, ub, gb, S_LEN * FF_DIM);
        conv(Wd + (long)l * H_DIM * FF_DIM, (long)H_DIM * FF_DIM);
        gemm_bt<1><<<dim3(H_DIM / 64, S_LEN / 64), 256, 0, stream>>>(gb, wt, x, S_LEN, H_DIM, FF_DIM);
    }

    copy_out_k<<<(out_size / 4 + 255) / 256, 256, 0, stream>>>(x, (float*)d_out, out_size / 4);
}

// Round 5
// 754.944 us; speedup vs baseline: 11.5416x; 11.5416x over previous
//
#include <hip/hip_runtime.h>
#include <math.h>

#define S_LEN 2048
#define H_DIM 1024
#define NHQ 16
#define D_HEAD 64
#define FF_DIM 4096
#define NLAYER 2
#define EPSV 1e-6f

typedef unsigned short ushortt;
typedef __attribute__((ext_vector_type(8))) short bf16x8;
typedef __attribute__((ext_vector_type(4))) short bf16x4;
typedef __attribute__((ext_vector_type(4))) float f32x4;

__device__ __forceinline__ float bf2f(ushortt u) {
    union { float f; unsigned u; } c; c.u = ((unsigned)u) << 16; return c.f;
}
__device__ __forceinline__ ushortt f2bf(float f) {
    union { float f; unsigned u; } c; c.f = f;
    unsigned r = c.u + 0x7fff + ((c.u >> 16) & 1);
    return (ushortt)(r >> 16);
}

// ---------------- f32 -> bf16 convert (weights), 8 elems/thread ----------------
__global__ __launch_bounds__(256) void f2b_k(const float* __restrict__ in,
                                             ushortt* __restrict__ out, long n) {
    long i8 = ((long)blockIdx.x * 256 + threadIdx.x) * 8;
    if (i8 >= n) return;
    f32x4 a = *(const f32x4*)&in[i8];
    f32x4 b = *(const f32x4*)&in[i8 + 4];
    bf16x8 o;
    #pragma unroll
    for (int j = 0; j < 4; j++) { o[j] = (short)f2bf(a[j]); o[4 + j] = (short)f2bf(b[j]); }
    *(bf16x8*)&out[i8] = o;
}

// ---------------- embedding gather: x_f32[row] = embed[ids[row]] ----------------
__global__ __launch_bounds__(256) void gather_k(const int* __restrict__ ids,
                                                const float* __restrict__ emb,
                                                float* __restrict__ x) {
    int row = blockIdx.x, tid = threadIdx.x;
    long id = ids[row];
    f32x4 e = *((const f32x4*)emb + id * (H_DIM / 4) + tid);
    *(f32x4*)&x[(long)row * H_DIM + tid * 4] = e;
}

// ---------------- rmsnorm: h_bf16 = x * rsqrt(mean(x^2)+eps) * w ----------------
__global__ __launch_bounds__(256) void rmsnorm_k(const float* __restrict__ x,
                                                 const float* __restrict__ w,
                                                 ushortt* __restrict__ out) {
    __shared__ float red[4];
    int row = blockIdx.x, tid = threadIdx.x;
    f32x4 v = *(const f32x4*)&x[(long)row * H_DIM + tid * 4];
    float ss = v[0]*v[0] + v[1]*v[1] + v[2]*v[2] + v[3]*v[3];
    #pragma unroll
    for (int off = 1; off < 64; off <<= 1) ss += __shfl_xor(ss, off, 64);
    if ((tid & 63) == 0) red[tid >> 6] = ss;
    __syncthreads();
    float tot = red[0] + red[1] + red[2] + red[3];
    float rs = rsqrtf(tot / (float)H_DIM + EPSV);
    f32x4 wv = *(const f32x4*)&w[tid * 4];
    #pragma unroll
    for (int j = 0; j < 4; j++)
        out[(long)row * H_DIM + tid * 4 + j] = f2bf(v[j] * rs * wv[j]);
}

// ---------------- GEMM: C[M,N] = A[M,K] * B[N,K]^T, bf16 in, MFMA ----------------
// EPI 0: out bf16 [M,N];  EPI 1: out f32 [M,N] += ;  EPI 2: out bf16 transposed [N,M]
template <int EPI>
__global__ __launch_bounds__(256) void gemm_bt(const ushortt* __restrict__ A,
                                               const ushortt* __restrict__ B,
                                               void* __restrict__ out,
                                               int M, int N, int K) {
    __shared__ ushortt As[64 * 40];
    __shared__ ushortt Bs[64 * 40];
    const int tid = threadIdx.x;
    const int lane = tid & 63;
    const int w = tid >> 6;
    const int wm = w >> 1, wn = w & 1;
    const int m0 = blockIdx.y * 64, n0 = blockIdx.x * 64;
    const int srow = tid >> 2, sc8 = (tid & 3) * 8;
    const int r15 = lane & 15, g = lane >> 4;

    f32x4 acc[2][2] = {};

    for (int k0 = 0; k0 < K; k0 += 32) {
        *(bf16x8*)&As[srow * 40 + sc8] = *(const bf16x8*)&A[(long)(m0 + srow) * K + k0 + sc8];
        *(bf16x8*)&Bs[srow * 40 + sc8] = *(const bf16x8*)&B[(long)(n0 + srow) * K + k0 + sc8];
        __syncthreads();
        bf16x8 a[2], b[2];
        #pragma unroll
        for (int m = 0; m < 2; m++) a[m] = *(bf16x8*)&As[(wm * 32 + m * 16 + r15) * 40 + g * 8];
        #pragma unroll
        for (int n = 0; n < 2; n++) b[n] = *(bf16x8*)&Bs[(wn * 32 + n * 16 + r15) * 40 + g * 8];
        #pragma unroll
        for (int m = 0; m < 2; m++)
            #pragma unroll
            for (int n = 0; n < 2; n++)
                acc[m][n] = __builtin_amdgcn_mfma_f32_16x16x32_bf16(a[m], b[n], acc[m][n], 0, 0, 0);
        __syncthreads();
    }

    #pragma unroll
    for (int m = 0; m < 2; m++)
        #pragma unroll
        for (int n = 0; n < 2; n++)
            #pragma unroll
            for (int r = 0; r < 4; r++) {
                int row = m0 + wm * 32 + m * 16 + g * 4 + r;
                int col = n0 + wn * 32 + n * 16 + r15;
                float v = acc[m][n][r];
                if (EPI == 0) ((ushortt*)out)[(long)row * N + col] = f2bf(v);
                else if (EPI == 1) ((float*)out)[(long)row * N + col] += v;
                else ((ushortt*)out)[(long)col * M + row] = f2bf(v);
            }
}

// ---------------- RoPE (rotate-half), in place on bf16 [S, nheads*64] ----------------
__global__ __launch_bounds__(256) void rope_k(ushortt* __restrict__ p, int nheads) {
    int idx = blockIdx.x * 256 + threadIdx.x;
    int total = S_LEN * nheads * 32;
    if (idx >= total) return;
    int i = idx & 31;
    int hd = (idx >> 5) % nheads;
    int s = idx / (32 * nheads);
    long base = (long)s * (nheads * 64) + hd * 64 + i;
    float x1 = bf2f(p[base]), x2 = bf2f(p[base + 32]);
    float inv = expf(-((2.f * i) / 64.f) * 9.210340371976184f); // ln(10000)
    float f = (float)s * inv;
    float sn, cs;
    sincosf(f, &sn, &cs);
    p[base] = f2bf(x1 * cs - x2 * sn);
    p[base + 32] = f2bf(x2 * cs + x1 * sn);
}

// ---------------- flash attention (non-causal, MQA HKV=1), MFMA ----------------
// grid: (S/16, NHQ), block: 64 (1 wave). q:[S,H] roped, k:[S,64] roped, vt:[64,S]
__global__ __launch_bounds__(64) void attn_k(const ushortt* __restrict__ q,
                                             const ushortt* __restrict__ k,
                                             const ushortt* __restrict__ vt,
                                             ushortt* __restrict__ o) {
    __shared__ ushortt P[16 * 40];
    const int lane = threadIdx.x;
    const int r15 = lane & 15, g = lane >> 4;
    const int h = blockIdx.y;
    const int q0 = blockIdx.x * 16;

    // Q B-fragment: B[k=d][col=query r15], k split dd*32 + g*8 + j
    bf16x8 bq[2];
    #pragma unroll
    for (int dd = 0; dd < 2; dd++)
        bq[dd] = *(const bf16x8*)&q[(long)(q0 + r15) * H_DIM + h * D_HEAD + dd * 32 + g * 8];

    f32x4 accO[4] = {};
    float mrun = -INFINITY, lrun = 0.f;

    for (int j0 = 0; j0 < S_LEN; j0 += 32) {
        // S^T tile = mfma(K-frag, Q-frag): D[key][query], lane column = query r15
        f32x4 s[2] = {};
        #pragma unroll
        for (int kt = 0; kt < 2; kt++)
            #pragma unroll
            for (int dd = 0; dd < 2; dd++) {
                bf16x8 ak = *(const bf16x8*)&k[(long)(j0 + kt * 16 + r15) * D_HEAD + dd * 32 + g * 8];
                s[kt] = __builtin_amdgcn_mfma_f32_16x16x32_bf16(ak, bq[dd], s[kt], 0, 0, 0);
            }
        // online softmax over the 32 keys; per-query state lives on lanes with same r15
        float pmax = -INFINITY;
        #pragma unroll
        for (int kt = 0; kt < 2; kt++)
            #pragma unroll
            for (int r = 0; r < 4; r++) { s[kt][r] *= 0.125f; pmax = fmaxf(pmax, s[kt][r]); }
        pmax = fmaxf(pmax, __shfl_xor(pmax, 16, 64));
        pmax = fmaxf(pmax, __shfl_xor(pmax, 32, 64));
        float mnew = fmaxf(mrun, pmax);
        float alpha = __expf(mrun - mnew);
        float psum = 0.f;
        ushortt pb[2][4];
        #pragma unroll
        for (int kt = 0; kt < 2; kt++)
            #pragma unroll
            for (int r = 0; r < 4; r++) {
                float pv = __expf(s[kt][r] - mnew);
                psum += pv;
                pb[kt][r] = f2bf(pv);
            }
        psum += __shfl_xor(psum, 16, 64);
        psum += __shfl_xor(psum, 32, 64);
        lrun = lrun * alpha + psum;
        mrun = mnew;
        #pragma unroll
        for (int dt = 0; dt < 4; dt++)
            #pragma unroll
            for (int r = 0; r < 4; r++) accO[dt][r] *= alpha;

        __syncthreads(); // previous iteration's P reads done
        // store P[query r15][key kt*16+g*4+r] as packed bf16
        #pragma unroll
        for (int kt = 0; kt < 2; kt++) {
            unsigned lo = (unsigned)pb[kt][0] | ((unsigned)pb[kt][1] << 16);
            unsigned hi = (unsigned)pb[kt][2] | ((unsigned)pb[kt][3] << 16);
            uint2 val; val.x = lo; val.y = hi;
            *(uint2*)&P[r15 * 40 + kt * 16 + g * 4] = val;
        }
        __syncthreads();

        // O^T += mfma(V^T-frag, P-frag): D[d][query], lane column = query r15
        bf16x8 bp = *(bf16x8*)&P[r15 * 40 + g * 8];
        #pragma unroll
        for (int dt = 0; dt < 4; dt++) {
            bf16x8 av = *(const bf16x8*)&vt[(long)(dt * 16 + r15) * S_LEN + j0 + g * 8];
            accO[dt] = __builtin_amdgcn_mfma_f32_16x16x32_bf16(av, bp, accO[dt], 0, 0, 0);
        }
    }

    float inv = 1.f / lrun;
    #pragma unroll
    for (int dt = 0; dt < 4; dt++)
        #pragma unroll
        for (int r = 0; r < 4; r++)
            o[(long)(q0 + r15) * H_DIM + h * D_HEAD + dt * 16 + g * 4 + r] = f2bf(accO[dt][r] * inv);
}

// ---------------- silu(g)*u ----------------
__global__ __launch_bounds__(256) void silu_mul_k(const ushortt* __restrict__ g,
                                                  const ushortt* __restrict__ u,
                                                  ushortt* __restrict__ out, int n) {
    int idx = blockIdx.x * 256 + threadIdx.x;
    if (idx >= n) return;
    float a = bf2f(g[idx]);
    float b = bf2f(u[idx]);
    float r = (a / (1.f + __expf(-a))) * b;
    out[idx] = f2bf(r);
}

// ---------------- final copy f32 -> f32 out ----------------
__global__ __launch_bounds__(256) void copy_out_k(const float* __restrict__ x,
                                                  float* __restrict__ out, int n4) {
    int idx = blockIdx.x * 256 + threadIdx.x;
    if (idx >= n4) return;
    *(f32x4*)&out[(long)idx * 4] = *(const f32x4*)&x[(long)idx * 4];
}

extern "C" void kernel_launch(void* const* d_in, const int* in_sizes, int n_in,
                              void* d_out, int out_size, void* d_ws, size_t ws_size,
                              hipStream_t stream) {
    const int* ids = (const int*)d_in[0];
    const float* emb = (const float*)d_in[1];
    const float* Wq = (const float*)d_in[2];
    const float* Wk = (const float*)d_in[3];
    const float* Wv = (const float*)d_in[4];
    const float* Wo = (const float*)d_in[5];
    const float* Wg = (const float*)d_in[6];
    const float* Wu = (const float*)d_in[7];
    const float* Wd = (const float*)d_in[8];
    const float* ln1 = (const float*)d_in[9];
    const float* ln2 = (const float*)d_in[10];

    char* ws = (char*)d_ws;
    float* x = (float*)ws;        ws += (size_t)S_LEN * H_DIM * 4;
    ushortt* h = (ushortt*)ws;    ws += (size_t)S_LEN * H_DIM * 2;
    ushortt* qb = (ushortt*)ws;   ws += (size_t)S_LEN * H_DIM * 2;
    ushortt* kb = (ushortt*)ws;   ws += (size_t)S_LEN * D_HEAD * 2;
    ushortt* vt = (ushortt*)ws;   ws += (size_t)S_LEN * D_HEAD * 2;
    ushortt* ob = (ushortt*)ws;   ws += (size_t)S_LEN * H_DIM * 2;
    ushortt* gb = (ushortt*)ws;   ws += (size_t)S_LEN * FF_DIM * 2;
    ushortt* ub = (ushortt*)ws;   ws += (size_t)S_LEN * FF_DIM * 2;
    ushortt* wt = (ushortt*)ws;   ws += (size_t)FF_DIM * H_DIM * 2;  // weight convert scratch

    auto conv = [&](const float* src, long n) {
        f2b_k<<<(int)((n / 8 + 255) / 256), 256, 0, stream>>>(src, wt, n);
    };

    gather_k<<<S_LEN, 256, 0, stream>>>(ids, emb, x);

    for (int l = 0; l < NLAYER; l++) {
        rmsnorm_k<<<S_LEN, 256, 0, stream>>>(x, ln1 + (long)l * H_DIM, h);

        conv(Wq + (long)l * H_DIM * H_DIM, (long)H_DIM * H_DIM);
        gemm_bt<0><<<dim3(H_DIM / 64, S_LEN / 64), 256, 0, stream>>>(h, wt, qb, S_LEN, H_DIM, H_DIM);
        conv(Wk + (long)l * D_HEAD * H_DIM, (long)D_HEAD * H_DIM);
        gemm_bt<0><<<dim3(1, S_LEN / 64), 256, 0, stream>>>(h, wt, kb, S_LEN, D_HEAD, H_DIM);
        conv(Wv + (long)l * D_HEAD * H_DIM, (long)D_HEAD * H_DIM);
        gemm_bt<2><<<dim3(1, S_LEN / 64), 256, 0, stream>>>(h, wt, vt, S_LEN, D_HEAD, H_DIM);

        rope_k<<<(S_LEN * NHQ * 32 + 255) / 256, 256, 0, stream>>>(qb, NHQ);
        rope_k<<<(S_LEN * 1 * 32 + 255) / 256, 256, 0, stream>>>(kb, 1);
        attn_k<<<dim3(S_LEN / 16, NHQ), 64, 0, stream>>>(qb, kb, vt, ob);

        conv(Wo + (long)l * H_DIM * H_DIM, (long)H_DIM * H_DIM);
        gemm_bt<1><<<dim3(H_DIM / 64, S_LEN / 64), 256, 0, stream>>>(ob, wt, x, S_LEN, H_DIM, H_DIM);

        rmsnorm_k<<<S_LEN, 256, 0, stream>>>(x, ln2 + (long)l * H_DIM, h);

        conv(Wg + (long)l * FF_DIM * H_DIM, (long)FF_DIM * H_DIM);
        gemm_bt<0><<<dim3(FF_DIM / 64, S_LEN / 64), 256, 0, stream>>>(h, wt, gb, S_LEN, FF_DIM, H_DIM);
        conv(Wu + (long)l * FF_DIM * H_DIM, (long)FF_DIM * H_DIM);
        gemm_bt<0><<<dim3(FF_DIM / 64, S_LEN / 64), 256, 0, stream>>>(h, wt, ub, S_LEN, FF_DIM, H_DIM);
        silu_mul_k<<<(S_LEN * FF_DIM + 255) / 256, 256, 0, stream>>>(gb, ub, gb, S_LEN * FF_DIM);
        conv(Wd + (long)l * H_DIM * FF_DIM, (long)H_DIM * FF_DIM);
        gemm_bt<1><<<dim3(H_DIM / 64, S_LEN / 64), 256, 0, stream>>>(gb, wt, x, S_LEN, H_DIM, FF_DIM);
    }

    copy_out_k<<<(out_size / 4 + 255) / 256, 256, 0, stream>>>(x, (float*)d_out, out_size / 4);
}